// Round 1
// baseline (1040.655 us; speedup 1.0000x reference)
//
#include <hip/hip_runtime.h>
#include <hip/hip_bf16.h>
#include <math.h>

// Problem constants (ProteinMPNN encoder stack)
#define BB 2
#define NN 1024
#define KK 48
#define HH 128
#define LL 3
// LDS row strides (bf16 elems), padded for bank-conflict avoidance + 16B align
#define SA 392   // 384 + 8
#define SY 136   // 128 + 8

typedef __attribute__((ext_vector_type(8))) short s8v;   // 8 bf16 (4 VGPRs)
typedef __attribute__((ext_vector_type(4))) float f4v;   // MFMA accumulator

static __device__ __forceinline__ unsigned short f2bf(float x) {
  union { float f; unsigned u; } v; v.f = x;
  unsigned r = v.u + 0x7FFFu + ((v.u >> 16) & 1u);  // RNE
  return (unsigned short)(r >> 16);
}
static __device__ __forceinline__ float geluf(float x) {
  return 0.5f * x * (1.0f + erff(x * 0.70710678118654752f));
}

// Wave-level GEMM: A (48 x KD bf16, LDS, row stride SAe) x W^T (128 x KD bf16, global).
// Wave `wave` computes cols [wave*32, wave*32+32) for all 48 rows.
template<int KD, int SAe>
static __device__ __forceinline__ void gemm48(const unsigned short* __restrict__ A,
                                              const unsigned short* __restrict__ Wt,
                                              int wave, int lane, f4v acc[3][2]) {
  const int g = lane >> 4, q = lane & 15;
  const unsigned short* wb0 = Wt + (wave * 32 + q) * KD;
  const unsigned short* wb1 = Wt + (wave * 32 + 16 + q) * KD;
#pragma unroll
  for (int t = 0; t < KD / 32; ++t) {
    const int k0 = t * 32 + g * 8;
    s8v a0 = *(const s8v*)(A + q * SAe + k0);
    s8v a1 = *(const s8v*)(A + (16 + q) * SAe + k0);
    s8v a2 = *(const s8v*)(A + (32 + q) * SAe + k0);
    s8v b0 = *(const s8v*)(wb0 + k0);
    s8v b1 = *(const s8v*)(wb1 + k0);
    acc[0][0] = __builtin_amdgcn_mfma_f32_16x16x32_bf16(a0, b0, acc[0][0], 0, 0, 0);
    acc[1][0] = __builtin_amdgcn_mfma_f32_16x16x32_bf16(a1, b0, acc[1][0], 0, 0, 0);
    acc[2][0] = __builtin_amdgcn_mfma_f32_16x16x32_bf16(a2, b0, acc[2][0], 0, 0, 0);
    acc[0][1] = __builtin_amdgcn_mfma_f32_16x16x32_bf16(a0, b1, acc[0][1], 0, 0, 0);
    acc[1][1] = __builtin_amdgcn_mfma_f32_16x16x32_bf16(a1, b1, acc[1][1], 0, 0, 0);
    acc[2][1] = __builtin_amdgcn_mfma_f32_16x16x32_bf16(a2, b1, acc[2][1], 0, 0, 0);
  }
}

static __device__ __forceinline__ void zero_acc(f4v acc[3][2]) {
#pragma unroll
  for (int rt = 0; rt < 3; ++rt)
#pragma unroll
    for (int c = 0; c < 2; ++c) acc[rt][c] = (f4v){0.f, 0.f, 0.f, 0.f};
}

// Write acc (+bias, optional gelu) to LDS Y as bf16.  C layout: col=lane&15, row=(lane>>4)*4+r.
static __device__ __forceinline__ void store_act(const f4v acc[3][2], unsigned short* __restrict__ Y,
                                                 int wave, int lane, const float* __restrict__ bias,
                                                 bool dog) {
  const int g = lane >> 4, q = lane & 15;
#pragma unroll
  for (int c = 0; c < 2; ++c) {
    const int col = wave * 32 + c * 16 + q;
    const float bv = bias[col];
#pragma unroll
    for (int rt = 0; rt < 3; ++rt)
#pragma unroll
      for (int r = 0; r < 4; ++r) {
        const int row = rt * 16 + g * 4 + r;
        float v = acc[rt][c][r] + bv;
        if (dog) v = geluf(v);
        Y[row * SY + col] = f2bf(v);
      }
  }
}

// ---------------- weight convert+transpose (f32 -> bf16, Wt[n][k]) ----------------
__global__ void conv_weights(const float* __restrict__ W1, const float* __restrict__ W2,
                             const float* __restrict__ W3, const float* __restrict__ W11,
                             const float* __restrict__ W12, const float* __restrict__ W13,
                             const float* __restrict__ Win, const float* __restrict__ Wout,
                             unsigned short* __restrict__ W1t, unsigned short* __restrict__ W2t,
                             unsigned short* __restrict__ W3t, unsigned short* __restrict__ W11t,
                             unsigned short* __restrict__ W12t, unsigned short* __restrict__ W13t,
                             unsigned short* __restrict__ Wint, unsigned short* __restrict__ Woutt) {
  const int tid = blockIdx.x * blockDim.x + threadIdx.x;
  const int nt = gridDim.x * blockDim.x;
  for (int i = tid; i < LL * 384 * 128; i += nt) {      // [L][384][128] -> [L][128][384]
    int l = i / (384 * 128), rem = i - l * 384 * 128;
    int k = rem / 128, n = rem - k * 128;
    W1t [(l * 128 + n) * 384 + k] = f2bf(W1[i]);
    W11t[(l * 128 + n) * 384 + k] = f2bf(W11[i]);
  }
  for (int i = tid; i < LL * 128 * 128; i += nt) {      // [L][128][128] -> transposed
    int l = i / (128 * 128), rem = i - l * 128 * 128;
    int k = rem / 128, n = rem - k * 128;
    W2t [(l * 128 + n) * 128 + k] = f2bf(W2[i]);
    W3t [(l * 128 + n) * 128 + k] = f2bf(W3[i]);
    W12t[(l * 128 + n) * 128 + k] = f2bf(W12[i]);
    W13t[(l * 128 + n) * 128 + k] = f2bf(W13[i]);
  }
  for (int i = tid; i < LL * 128 * 512; i += nt) {      // Win [L][128][512] -> [L][512][128]
    int l = i / (128 * 512), rem = i - l * 128 * 512;
    int k = rem / 512, u = rem - k * 512;
    Wint[(l * 512 + u) * 128 + k] = f2bf(Win[i]);
  }
  for (int i = tid; i < LL * 512 * 128; i += nt) {      // Wout [L][512][128] -> [L][128][512]
    int l = i / (512 * 128), rem = i - l * 512 * 128;
    int k = rem / 128, n = rem - k * 128;
    Woutt[(l * 128 + n) * 512 + k] = f2bf(Wout[i]);
  }
}

// ---------------- node update: message MLP + aggregate + LN1 + FFN + LN2 ----------------
__global__ __launch_bounds__(256, 2) void node_kernel(
    const float* __restrict__ hv_in, const float* __restrict__ hE_in,
    const int* __restrict__ eidx, const float* __restrict__ mask_att,
    const float* __restrict__ mask_V,
    const unsigned short* __restrict__ W1t, const unsigned short* __restrict__ W2t,
    const unsigned short* __restrict__ W3t,
    const float* __restrict__ b1, const float* __restrict__ b2, const float* __restrict__ b3,
    const unsigned short* __restrict__ Wint, const float* __restrict__ binp,
    const unsigned short* __restrict__ Woutt, const float* __restrict__ boutp,
    const float* __restrict__ g1, const float* __restrict__ be1,
    const float* __restrict__ g2, const float* __restrict__ be2,
    float* __restrict__ hv_out) {
  __shared__ __align__(16) unsigned short shA[48 * SA];
  __shared__ __align__(16) unsigned short shY1[48 * SY];
  __shared__ __align__(16) unsigned short shY2[48 * SY];
  __shared__ int sh_idx[48];
  __shared__ float sh_mask[48];
  __shared__ float sh_hv[128];
  __shared__ float sh_x[128];
  __shared__ float sh_h1[128];
  __shared__ float sh_hid[512];
  __shared__ float sh_st[2];

  const int tid = threadIdx.x;
  const int lane = tid & 63, wave = tid >> 6;
  const int bid = blockIdx.x;         // b*N + n
  const int b = bid >> 10;

  if (tid < 48) { sh_idx[tid] = eidx[bid * 48 + tid]; sh_mask[tid] = mask_att[bid * 48 + tid]; }
  if (tid < 128) sh_hv[tid] = hv_in[(size_t)bid * 128 + tid];
  __syncthreads();

  const float* hEr = hE_in + (size_t)bid * (48 * 128);
  for (int e = tid; e < 48 * 384; e += 256) {
    int row = e / 384, c = e - row * 384;
    float v;
    if (c < 128)       v = sh_hv[c];
    else if (c < 256)  v = hEr[row * 128 + (c - 128)];
    else               v = hv_in[((size_t)(b * 1024 + sh_idx[row])) * 128 + (c - 256)];
    shA[row * SA + c] = f2bf(v);
  }
  __syncthreads();

  f4v acc[3][2];
  zero_acc(acc);
  gemm48<384, SA>(shA, W1t, wave, lane, acc);
  store_act(acc, shY1, wave, lane, b1, true);
  __syncthreads();

  zero_acc(acc);
  gemm48<128, SY>(shY1, W2t, wave, lane, acc);
  store_act(acc, shY2, wave, lane, b2, true);
  __syncthreads();

  zero_acc(acc);
  gemm48<128, SY>(shY2, W3t, wave, lane, acc);

  // masked sum over 48 edges, /SCALE, + residual  (bias b3 folded via mask sum)
  const int g = lane >> 4, q = lane & 15;
  float msum = 0.f;
#pragma unroll
  for (int k = 0; k < 48; ++k) msum += sh_mask[k];
  float p0 = 0.f, p1 = 0.f;
#pragma unroll
  for (int rt = 0; rt < 3; ++rt)
#pragma unroll
    for (int r = 0; r < 4; ++r) {
      const int row = rt * 16 + g * 4 + r;
      const float mk = sh_mask[row];
      p0 += acc[rt][0][r] * mk;
      p1 += acc[rt][1][r] * mk;
    }
  p0 += __shfl_xor(p0, 16); p0 += __shfl_xor(p0, 32);
  p1 += __shfl_xor(p1, 16); p1 += __shfl_xor(p1, 32);
  if (g == 0) {
    const int c0 = wave * 32 + q, c1 = wave * 32 + 16 + q;
    sh_x[c0] = sh_hv[c0] + (p0 + b3[c0] * msum) * (1.f / 30.f);
    sh_x[c1] = sh_hv[c1] + (p1 + b3[c1] * msum) * (1.f / 30.f);
  }
  __syncthreads();

  // LN1
  if (tid < 64) {
    float a = sh_x[tid], c2 = sh_x[tid + 64];
    float s = a + c2, ss = a * a + c2 * c2;
#pragma unroll
    for (int off = 32; off; off >>= 1) { s += __shfl_xor(s, off); ss += __shfl_xor(ss, off); }
    if (tid == 0) { float mu = s * (1.f / 128.f); sh_st[0] = mu; sh_st[1] = ss * (1.f / 128.f) - mu * mu; }
  }
  __syncthreads();
  if (tid < 128) {
    float mu = sh_st[0], rs = rsqrtf(sh_st[1] + 1e-5f);
    sh_h1[tid] = g1[tid] * (sh_x[tid] - mu) * rs + be1[tid];
  }
  __syncthreads();

  // FFN: 128 -> 512 (gelu) -> 128, bf16 weights, f32 accumulate
#pragma unroll
  for (int rep = 0; rep < 2; ++rep) {
    const int u = tid + rep * 256;
    const uint4* wr = (const uint4*)(Wint + (size_t)u * 128);
    float s = binp[u];
#pragma unroll
    for (int k8 = 0; k8 < 16; ++k8) {
      uint4 w = wr[k8];
      const float* h8 = sh_h1 + k8 * 8;
      s += h8[0] * __uint_as_float(w.x << 16) + h8[1] * __uint_as_float(w.x & 0xffff0000u)
         + h8[2] * __uint_as_float(w.y << 16) + h8[3] * __uint_as_float(w.y & 0xffff0000u)
         + h8[4] * __uint_as_float(w.z << 16) + h8[5] * __uint_as_float(w.z & 0xffff0000u)
         + h8[6] * __uint_as_float(w.w << 16) + h8[7] * __uint_as_float(w.w & 0xffff0000u);
    }
    sh_hid[u] = geluf(s);
  }
  __syncthreads();
  if (tid < 128) {
    const uint4* wr = (const uint4*)(Woutt + (size_t)tid * 512);
    float s = boutp[tid];
#pragma unroll 8
    for (int k8 = 0; k8 < 64; ++k8) {
      uint4 w = wr[k8];
      const float* h8 = sh_hid + k8 * 8;
      s += h8[0] * __uint_as_float(w.x << 16) + h8[1] * __uint_as_float(w.x & 0xffff0000u)
         + h8[2] * __uint_as_float(w.y << 16) + h8[3] * __uint_as_float(w.y & 0xffff0000u)
         + h8[4] * __uint_as_float(w.z << 16) + h8[5] * __uint_as_float(w.z & 0xffff0000u)
         + h8[6] * __uint_as_float(w.w << 16) + h8[7] * __uint_as_float(w.w & 0xffff0000u);
    }
    sh_x[tid] = sh_h1[tid] + s;   // residual
  }
  __syncthreads();

  // LN2 + mask_V + write
  if (tid < 64) {
    float a = sh_x[tid], c2 = sh_x[tid + 64];
    float s = a + c2, ss = a * a + c2 * c2;
#pragma unroll
    for (int off = 32; off; off >>= 1) { s += __shfl_xor(s, off); ss += __shfl_xor(ss, off); }
    if (tid == 0) { float mu = s * (1.f / 128.f); sh_st[0] = mu; sh_st[1] = ss * (1.f / 128.f) - mu * mu; }
  }
  __syncthreads();
  if (tid < 128) {
    float mu = sh_st[0], rs = rsqrtf(sh_st[1] + 1e-5f);
    float v = g2[tid] * (sh_x[tid] - mu) * rs + be2[tid];
    hv_out[(size_t)bid * 128 + tid] = mask_V[bid] * v;
  }
}

// ---------------- edge update: message MLP + LN3, in-place h_E ----------------
__global__ __launch_bounds__(256, 2) void edge_kernel(
    const float* __restrict__ hv, const float* __restrict__ hE_in,
    const int* __restrict__ eidx,
    const unsigned short* __restrict__ W11t, const unsigned short* __restrict__ W12t,
    const unsigned short* __restrict__ W13t,
    const float* __restrict__ b11, const float* __restrict__ b12, const float* __restrict__ b13,
    const float* __restrict__ g3, const float* __restrict__ be3,
    float* __restrict__ hE_out) {
  __shared__ __align__(16) union { unsigned short A[48 * SA]; float M[48 * 128]; } shAM;
  __shared__ __align__(16) unsigned short shY1[48 * SY];
  __shared__ __align__(16) unsigned short shY2[48 * SY];
  __shared__ int sh_idx[48];
  __shared__ float sh_hv[128];

  const int tid = threadIdx.x;
  const int lane = tid & 63, wave = tid >> 6;
  const int bid = blockIdx.x;
  const int b = bid >> 10;

  if (tid < 48) sh_idx[tid] = eidx[bid * 48 + tid];
  if (tid < 128) sh_hv[tid] = hv[(size_t)bid * 128 + tid];
  __syncthreads();

  const float* hEr = hE_in + (size_t)bid * (48 * 128);
  for (int e = tid; e < 48 * 384; e += 256) {
    int row = e / 384, c = e - row * 384;
    float v;
    if (c < 128)       v = sh_hv[c];
    else if (c < 256)  v = hEr[row * 128 + (c - 128)];
    else               v = hv[((size_t)(b * 1024 + sh_idx[row])) * 128 + (c - 256)];
    shAM.A[row * SA + c] = f2bf(v);
  }
  __syncthreads();

  f4v acc[3][2];
  zero_acc(acc);
  gemm48<384, SA>(shAM.A, W11t, wave, lane, acc);
  store_act(acc, shY1, wave, lane, b11, true);
  __syncthreads();

  zero_acc(acc);
  gemm48<128, SY>(shY1, W12t, wave, lane, acc);
  store_act(acc, shY2, wave, lane, b12, true);
  __syncthreads();

  zero_acc(acc);
  gemm48<128, SY>(shY2, W13t, wave, lane, acc);
  __syncthreads();   // everyone done reading shAM.A before aliasing as M

  const int g = lane >> 4, q = lane & 15;
#pragma unroll
  for (int c = 0; c < 2; ++c) {
    const int col = wave * 32 + c * 16 + q;
    const float bv = b13[col];
#pragma unroll
    for (int rt = 0; rt < 3; ++rt)
#pragma unroll
      for (int r = 0; r < 4; ++r) {
        const int row = rt * 16 + g * 4 + r;
        shAM.M[row * 128 + col] = acc[rt][c][r] + bv;
      }
  }
  __syncthreads();

  // per-row LayerNorm with residual from ORIGINAL f32 h_E; 12 rows per wave
  const float* heb = hE_in + (size_t)bid * (48 * 128);
  float* hob = hE_out + (size_t)bid * (48 * 128);
#pragma unroll 1
  for (int i = 0; i < 12; ++i) {
    const int row = wave * 12 + i;
    float x0 = heb[row * 128 + lane]      + shAM.M[row * 128 + lane];
    float x1 = heb[row * 128 + 64 + lane] + shAM.M[row * 128 + 64 + lane];
    float s = x0 + x1, ss = x0 * x0 + x1 * x1;
#pragma unroll
    for (int off = 32; off; off >>= 1) { s += __shfl_xor(s, off); ss += __shfl_xor(ss, off); }
    const float mu = s * (1.f / 128.f);
    const float rs = rsqrtf(ss * (1.f / 128.f) - mu * mu + 1e-5f);
    hob[row * 128 + lane]      = g3[lane]      * (x0 - mu) * rs + be3[lane];
    hob[row * 128 + 64 + lane] = g3[lane + 64] * (x1 - mu) * rs + be3[lane + 64];
  }
}

extern "C" void kernel_launch(void* const* d_in, const int* in_sizes, int n_in,
                              void* d_out, int out_size, void* d_ws, size_t ws_size,
                              hipStream_t stream) {
  const float* h_V      = (const float*)d_in[0];
  const float* h_E      = (const float*)d_in[1];
  const int*   E_idx    = (const int*)d_in[2];
  const float* mask_V   = (const float*)d_in[3];
  const float* mask_att = (const float*)d_in[4];
  const float* W1   = (const float*)d_in[5];   const float* b1   = (const float*)d_in[6];
  const float* W2   = (const float*)d_in[7];   const float* b2   = (const float*)d_in[8];
  const float* W3   = (const float*)d_in[9];   const float* b3   = (const float*)d_in[10];
  const float* W11  = (const float*)d_in[11];  const float* b11  = (const float*)d_in[12];
  const float* W12  = (const float*)d_in[13];  const float* b12  = (const float*)d_in[14];
  const float* W13  = (const float*)d_in[15];  const float* b13  = (const float*)d_in[16];
  const float* Win  = (const float*)d_in[17];  const float* binp = (const float*)d_in[18];
  const float* Wout = (const float*)d_in[19];  const float* boutp= (const float*)d_in[20];
  const float* g1   = (const float*)d_in[21];  const float* be1  = (const float*)d_in[22];
  const float* g2   = (const float*)d_in[23];  const float* be2  = (const float*)d_in[24];
  const float* g3   = (const float*)d_in[25];  const float* be3  = (const float*)d_in[26];

  float* outV = (float*)d_out;                 // [2,1024,128]
  float* outE = outV + (size_t)BB * NN * HH;   // [2,1024,48,128]

  unsigned short* ws   = (unsigned short*)d_ws;
  unsigned short* W1t  = ws;                          // 3*128*384
  unsigned short* W2t  = W1t  + 3 * 128 * 384;        // 3*128*128
  unsigned short* W3t  = W2t  + 3 * 128 * 128;
  unsigned short* W11t = W3t  + 3 * 128 * 128;
  unsigned short* W12t = W11t + 3 * 128 * 384;
  unsigned short* W13t = W12t + 3 * 128 * 128;
  unsigned short* Wint = W13t + 3 * 128 * 128;        // 3*512*128
  unsigned short* Woutt= Wint + 3 * 512 * 128;        // 3*128*512
  float* hvA = (float*)(Woutt + 3 * 128 * 512);       // ping-pong h_V buffers
  float* hvB = hvA + (size_t)BB * NN * HH;

  conv_weights<<<512, 256, 0, stream>>>(W1, W2, W3, W11, W12, W13, Win, Wout,
                                        W1t, W2t, W3t, W11t, W12t, W13t, Wint, Woutt);

  for (int l = 0; l < LL; ++l) {
    const float* hv_in  = (l == 0) ? h_V : ((l == 1) ? hvA : hvB);
    float*       hv_mid = (l == 0) ? hvA : ((l == 1) ? hvB : outV);
    const float* hE_src = (l == 0) ? h_E : outE;

    node_kernel<<<BB * NN, 256, 0, stream>>>(
        hv_in, hE_src, E_idx, mask_att, mask_V,
        W1t + l * 128 * 384, W2t + l * 128 * 128, W3t + l * 128 * 128,
        b1 + l * 128, b2 + l * 128, b3 + l * 128,
        Wint + l * 512 * 128, binp + l * 512, Woutt + l * 128 * 512, boutp + l * 128,
        g1 + l * 128, be1 + l * 128, g2 + l * 128, be2 + l * 128,
        hv_mid);

    edge_kernel<<<BB * NN, 256, 0, stream>>>(
        hv_mid, hE_src, E_idx,
        W11t + l * 128 * 384, W12t + l * 128 * 128, W13t + l * 128 * 128,
        b11 + l * 128, b12 + l * 128, b13 + l * 128,
        g3 + l * 128, be3 + l * 128,
        outE);
  }
}

// Round 2
// 499.124 us; speedup vs baseline: 2.0850x; 2.0850x over previous
//
#include <hip/hip_runtime.h>
#include <hip/hip_bf16.h>
#include <math.h>

#define BB 2
#define NN 1024
#define KK 48
#define HH 128
#define LL 3
#define SA 392   // A-tile row stride (bf16 elems): 384+8, 16B-aligned rows (784B)
#define SY 136   // Y row stride: 128+8
#define SH 520   // FFN hidden row stride: 512+8

typedef __attribute__((ext_vector_type(8))) short s8v;   // 8 bf16
typedef __attribute__((ext_vector_type(4))) float f4v;   // MFMA acc
typedef unsigned short u16;

static __device__ __forceinline__ u16 f2bf(float x) {
  union { float f; unsigned u; } v; v.f = x;
  unsigned r = v.u + 0x7FFFu + ((v.u >> 16) & 1u);  // RNE
  return (u16)(r >> 16);
}
static __device__ __forceinline__ float geluf(float x) {
  return 0.5f * x * (1.0f + erff(x * 0.70710678118654752f));
}

// 48xKD (LDS) @ Wt[128][KD] (global, L2-hot). B-fragments prefetched to regs.
template<int KD, int SAe>
static __device__ __forceinline__ void gemm48(const u16* __restrict__ A,
                                              const u16* __restrict__ Wt,
                                              int wave, int lane, f4v acc[3][2]) {
  const int g = lane >> 4, q = lane & 15;
  constexpr int NT = KD / 32;
  s8v B0[NT], B1[NT];
  const u16* wb0 = Wt + (wave * 32 + q) * KD + g * 8;
  const u16* wb1 = wb0 + 16 * KD;
#pragma unroll
  for (int t = 0; t < NT; ++t) {
    B0[t] = *(const s8v*)(wb0 + t * 32);
    B1[t] = *(const s8v*)(wb1 + t * 32);
  }
#pragma unroll
  for (int t = 0; t < NT; ++t) {
    const u16* Ab = A + t * 32 + g * 8;
    s8v a0 = *(const s8v*)(Ab + q * SAe);
    s8v a1 = *(const s8v*)(Ab + (16 + q) * SAe);
    s8v a2 = *(const s8v*)(Ab + (32 + q) * SAe);
    acc[0][0] = __builtin_amdgcn_mfma_f32_16x16x32_bf16(a0, B0[t], acc[0][0], 0, 0, 0);
    acc[0][1] = __builtin_amdgcn_mfma_f32_16x16x32_bf16(a0, B1[t], acc[0][1], 0, 0, 0);
    acc[1][0] = __builtin_amdgcn_mfma_f32_16x16x32_bf16(a1, B0[t], acc[1][0], 0, 0, 0);
    acc[1][1] = __builtin_amdgcn_mfma_f32_16x16x32_bf16(a1, B1[t], acc[1][1], 0, 0, 0);
    acc[2][0] = __builtin_amdgcn_mfma_f32_16x16x32_bf16(a2, B0[t], acc[2][0], 0, 0, 0);
    acc[2][1] = __builtin_amdgcn_mfma_f32_16x16x32_bf16(a2, B1[t], acc[2][1], 0, 0, 0);
  }
}

static __device__ __forceinline__ void zero_acc(f4v acc[3][2]) {
#pragma unroll
  for (int rt = 0; rt < 3; ++rt)
#pragma unroll
    for (int c = 0; c < 2; ++c) acc[rt][c] = (f4v){0.f, 0.f, 0.f, 0.f};
}

// acc(+bias, gelu) -> LDS Y bf16. C layout: col=lane&15, row=(lane>>4)*4+r.
static __device__ __forceinline__ void store_act(const f4v acc[3][2], u16* __restrict__ Y,
                                                 int wave, int lane, const float* __restrict__ bias) {
  const int g = lane >> 4, q = lane & 15;
#pragma unroll
  for (int c = 0; c < 2; ++c) {
    const int col = wave * 32 + c * 16 + q;
    const float bv = bias[col];
#pragma unroll
    for (int rt = 0; rt < 3; ++rt)
#pragma unroll
      for (int r = 0; r < 4; ++r) {
        const int row = rt * 16 + g * 4 + r;
        Y[row * SY + col] = f2bf(geluf(acc[rt][c][r] + bv));
      }
  }
}

// Shared staging: build A = [hv_self | h_E | hv_gather] as bf16 in LDS.
static __device__ __forceinline__ void stage_A(u16* __restrict__ shA, const u16* __restrict__ hvbf,
                                               const float* __restrict__ hE_src,
                                               const int* __restrict__ sh_idx,
                                               int bid, int bbase, int tid) {
  const uint4* hvb = (const uint4*)(hvbf + (size_t)bid * 128);
#pragma unroll
  for (int p = 0; p < 3; ++p) {
    int i = tid + p * 256; int row = i >> 4, c = i & 15;
    *(uint4*)(shA + row * SA + c * 8) = hvb[c];
  }
  const float4* hEr = (const float4*)(hE_src + (size_t)bid * 6144);
#pragma unroll
  for (int p = 0; p < 6; ++p) {
    int i = tid + p * 256; int row = i >> 5, c = i & 31;
    float4 v = hEr[row * 32 + c];
    uint2 pk;
    pk.x = (unsigned)f2bf(v.x) | ((unsigned)f2bf(v.y) << 16);
    pk.y = (unsigned)f2bf(v.z) | ((unsigned)f2bf(v.w) << 16);
    *(uint2*)(shA + row * SA + 128 + c * 4) = pk;
  }
#pragma unroll
  for (int p = 0; p < 3; ++p) {
    int i = tid + p * 256; int row = i >> 4, c = i & 15;
    const uint4* src = (const uint4*)(hvbf + (size_t)(bbase + sh_idx[row]) * 128);
    *(uint4*)(shA + row * SA + 256 + c * 8) = src[c];
  }
}

// ---------------- weight/hv convert (f32 -> bf16, weights transposed) ----------------
__global__ void conv_weights(const float* __restrict__ W1, const float* __restrict__ W2,
                             const float* __restrict__ W3, const float* __restrict__ W11,
                             const float* __restrict__ W12, const float* __restrict__ W13,
                             const float* __restrict__ Win, const float* __restrict__ Wout,
                             const float* __restrict__ hV,
                             u16* __restrict__ W1t, u16* __restrict__ W2t,
                             u16* __restrict__ W3t, u16* __restrict__ W11t,
                             u16* __restrict__ W12t, u16* __restrict__ W13t,
                             u16* __restrict__ Wint, u16* __restrict__ Woutt,
                             u16* __restrict__ hv0bf) {
  const int tid = blockIdx.x * blockDim.x + threadIdx.x;
  const int nt = gridDim.x * blockDim.x;
  for (int i = tid; i < LL * 384 * 128; i += nt) {
    int l = i / (384 * 128), rem = i - l * 384 * 128;
    int k = rem / 128, n = rem - k * 128;
    W1t [(l * 128 + n) * 384 + k] = f2bf(W1[i]);
    W11t[(l * 128 + n) * 384 + k] = f2bf(W11[i]);
  }
  for (int i = tid; i < LL * 128 * 128; i += nt) {
    int l = i / (128 * 128), rem = i - l * 128 * 128;
    int k = rem / 128, n = rem - k * 128;
    W2t [(l * 128 + n) * 128 + k] = f2bf(W2[i]);
    W3t [(l * 128 + n) * 128 + k] = f2bf(W3[i]);
    W12t[(l * 128 + n) * 128 + k] = f2bf(W12[i]);
    W13t[(l * 128 + n) * 128 + k] = f2bf(W13[i]);
  }
  for (int i = tid; i < LL * 128 * 512; i += nt) {
    int l = i / (128 * 512), rem = i - l * 128 * 512;
    int k = rem / 512, u = rem - k * 512;
    Wint[(l * 512 + u) * 128 + k] = f2bf(Win[i]);
  }
  for (int i = tid; i < LL * 512 * 128; i += nt) {
    int l = i / (512 * 128), rem = i - l * 512 * 128;
    int k = rem / 128, n = rem - k * 128;
    Woutt[(l * 128 + n) * 512 + k] = f2bf(Wout[i]);
  }
  for (int i = tid; i < BB * NN * HH; i += nt) hv0bf[i] = f2bf(hV[i]);
}

// ---------------- node message: MLP + masked aggregate + LN1 ----------------
__global__ __launch_bounds__(256, 3) void node_msg(
    const float* __restrict__ hv_res, const u16* __restrict__ hvbf,
    const float* __restrict__ hE_src, const int* __restrict__ eidx,
    const float* __restrict__ mask_att,
    const u16* __restrict__ W1t, const u16* __restrict__ W2t, const u16* __restrict__ W3t,
    const float* __restrict__ b1, const float* __restrict__ b2, const float* __restrict__ b3,
    const float* __restrict__ g1, const float* __restrict__ be1,
    float* __restrict__ hv1, u16* __restrict__ hv1bf) {
  __shared__ __align__(16) u16 shA[48 * SA];   // Y2 aliased at u16 offset 12288
  __shared__ __align__(16) u16 shY1[48 * SY];
  __shared__ int sh_idx[48];
  __shared__ float sh_mask[48];
  __shared__ float sh_x[128];
  __shared__ float sh_st[2];

  const int tid = threadIdx.x, lane = tid & 63, wave = tid >> 6;
  const int bid = blockIdx.x, bbase = bid & ~(NN - 1);

  if (tid < 48) { sh_idx[tid] = eidx[bid * 48 + tid]; sh_mask[tid] = mask_att[bid * 48 + tid]; }
  __syncthreads();
  stage_A(shA, hvbf, hE_src, sh_idx, bid, bbase, tid);
  __syncthreads();

  f4v acc[3][2];
  zero_acc(acc);
  gemm48<384, SA>(shA, W1t, wave, lane, acc);
  store_act(acc, shY1, wave, lane, b1);
  __syncthreads();

  u16* shY2 = shA + 12288;   // bytes [24576, 37632) of shA — A is dead
  zero_acc(acc);
  gemm48<128, SY>(shY1, W2t, wave, lane, acc);
  store_act(acc, shY2, wave, lane, b2);
  __syncthreads();

  zero_acc(acc);
  gemm48<128, SY>(shY2, W3t, wave, lane, acc);

  const int g = lane >> 4, q = lane & 15;
  float msum = 0.f;
#pragma unroll
  for (int k = 0; k < 48; ++k) msum += sh_mask[k];
  float p0 = 0.f, p1 = 0.f;
#pragma unroll
  for (int rt = 0; rt < 3; ++rt)
#pragma unroll
    for (int r = 0; r < 4; ++r) {
      const int row = rt * 16 + g * 4 + r;
      const float mk = sh_mask[row];
      p0 += acc[rt][0][r] * mk;
      p1 += acc[rt][1][r] * mk;
    }
  p0 += __shfl_xor(p0, 16); p0 += __shfl_xor(p0, 32);
  p1 += __shfl_xor(p1, 16); p1 += __shfl_xor(p1, 32);
  if (g == 0) {
    const int c0 = wave * 32 + q, c1 = wave * 32 + 16 + q;
    sh_x[c0] = hv_res[(size_t)bid * 128 + c0] + (p0 + b3[c0] * msum) * (1.f / 30.f);
    sh_x[c1] = hv_res[(size_t)bid * 128 + c1] + (p1 + b3[c1] * msum) * (1.f / 30.f);
  }
  __syncthreads();

  if (tid < 64) {
    float a = sh_x[tid], c2 = sh_x[tid + 64];
    float s = a + c2, ss = a * a + c2 * c2;
#pragma unroll
    for (int off = 32; off; off >>= 1) { s += __shfl_xor(s, off); ss += __shfl_xor(ss, off); }
    if (tid == 0) { float mu = s * (1.f / 128.f); sh_st[0] = mu; sh_st[1] = ss * (1.f / 128.f) - mu * mu; }
  }
  __syncthreads();
  if (tid < 128) {
    float mu = sh_st[0], rs = rsqrtf(sh_st[1] + 1e-5f);
    float v = g1[tid] * (sh_x[tid] - mu) * rs + be1[tid];
    hv1[(size_t)bid * 128 + tid] = v;
    hv1bf[(size_t)bid * 128 + tid] = f2bf(v);
  }
}

// ---------------- FFN: batched [2048x128] -> 512 (gelu) -> 128, + LN2 + mask ----------------
__global__ __launch_bounds__(256) void ffn_kernel(
    const float* __restrict__ hv1, const u16* __restrict__ hv1bf,
    const u16* __restrict__ Wint, const float* __restrict__ binp,
    const u16* __restrict__ Woutt, const float* __restrict__ boutp,
    const float* __restrict__ g2, const float* __restrict__ be2,
    const float* __restrict__ mask_V,
    float* __restrict__ hv2, u16* __restrict__ hv2bf) {
  __shared__ __align__(16) u16 shX[16 * SY];
  __shared__ __align__(16) u16 shH[16 * SH];
  __shared__ float shM[16 * 128];
  const int tid = threadIdx.x, lane = tid & 63, wave = tid >> 6;
  const int g = lane >> 4, q = lane & 15;
  const int r0 = blockIdx.x * 16;

  {
    const uint4* src = (const uint4*)(hv1bf + (size_t)r0 * 128);
    int row = tid >> 4, c = tid & 15;
    *(uint4*)(shX + row * SY + c * 8) = src[tid];
  }
  __syncthreads();

  s8v a[4];
#pragma unroll
  for (int t = 0; t < 4; ++t) a[t] = *(const s8v*)(shX + q * SY + t * 32 + g * 8);
#pragma unroll
  for (int cf = 0; cf < 8; ++cf) {
    const int u = wave * 128 + cf * 16 + q;
    const u16* wb = Wint + (size_t)u * 128 + g * 8;
    f4v acc = (f4v){0.f, 0.f, 0.f, 0.f};
#pragma unroll
    for (int t = 0; t < 4; ++t)
      acc = __builtin_amdgcn_mfma_f32_16x16x32_bf16(a[t], *(const s8v*)(wb + t * 32), acc, 0, 0, 0);
    const float bv = binp[u];
#pragma unroll
    for (int r = 0; r < 4; ++r) shH[(g * 4 + r) * SH + u] = f2bf(geluf(acc[r] + bv));
  }
  __syncthreads();

#pragma unroll
  for (int c = 0; c < 2; ++c) {
    const int col = wave * 32 + c * 16 + q;
    const u16* wb = Woutt + (size_t)col * 512 + g * 8;
    s8v Bv[16];
#pragma unroll
    for (int t = 0; t < 16; ++t) Bv[t] = *(const s8v*)(wb + t * 32);
    f4v acc = (f4v){0.f, 0.f, 0.f, 0.f};
#pragma unroll
    for (int t = 0; t < 16; ++t) {
      s8v av = *(const s8v*)(shH + q * SH + t * 32 + g * 8);
      acc = __builtin_amdgcn_mfma_f32_16x16x32_bf16(av, Bv[t], acc, 0, 0, 0);
    }
    const float bv = boutp[col];
#pragma unroll
    for (int r = 0; r < 4; ++r) shM[(g * 4 + r) * 128 + col] = acc[r] + bv;
  }
  __syncthreads();

#pragma unroll
  for (int i = 0; i < 4; ++i) {
    const int row = wave * 4 + i, gr = r0 + row;
    float x0 = hv1[(size_t)gr * 128 + lane]      + shM[row * 128 + lane];
    float x1 = hv1[(size_t)gr * 128 + 64 + lane] + shM[row * 128 + 64 + lane];
    float s = x0 + x1, ss = x0 * x0 + x1 * x1;
#pragma unroll
    for (int off = 32; off; off >>= 1) { s += __shfl_xor(s, off); ss += __shfl_xor(ss, off); }
    const float mu = s * (1.f / 128.f);
    const float rs = rsqrtf(ss * (1.f / 128.f) - mu * mu + 1e-5f);
    const float mv = mask_V[gr];
    float o0 = mv * (g2[lane]      * (x0 - mu) * rs + be2[lane]);
    float o1 = mv * (g2[lane + 64] * (x1 - mu) * rs + be2[lane + 64]);
    hv2[(size_t)gr * 128 + lane] = o0;
    hv2[(size_t)gr * 128 + 64 + lane] = o1;
    hv2bf[(size_t)gr * 128 + lane] = f2bf(o0);
    hv2bf[(size_t)gr * 128 + 64 + lane] = f2bf(o1);
  }
}

// ---------------- edge update: MLP + LN3, in-place h_E ----------------
__global__ __launch_bounds__(256, 3) void edge_kernel(
    const u16* __restrict__ hvbf, const float* __restrict__ hE_src,
    const int* __restrict__ eidx,
    const u16* __restrict__ W11t, const u16* __restrict__ W12t, const u16* __restrict__ W13t,
    const float* __restrict__ b11, const float* __restrict__ b12, const float* __restrict__ b13,
    const float* __restrict__ g3, const float* __restrict__ be3,
    float* __restrict__ hE_out) {
  __shared__ __align__(16) u16 shA[48 * SA];   // M(f32) at bytes [0,24576), Y2 at u16 off 12288
  __shared__ __align__(16) u16 shY1[48 * SY];
  __shared__ int sh_idx[48];

  const int tid = threadIdx.x, lane = tid & 63, wave = tid >> 6;
  const int bid = blockIdx.x, bbase = bid & ~(NN - 1);

  if (tid < 48) sh_idx[tid] = eidx[bid * 48 + tid];
  __syncthreads();
  stage_A(shA, hvbf, hE_src, sh_idx, bid, bbase, tid);
  __syncthreads();

  f4v acc[3][2];
  zero_acc(acc);
  gemm48<384, SA>(shA, W11t, wave, lane, acc);
  store_act(acc, shY1, wave, lane, b11);
  __syncthreads();

  u16* shY2 = shA + 12288;
  zero_acc(acc);
  gemm48<128, SY>(shY1, W12t, wave, lane, acc);
  store_act(acc, shY2, wave, lane, b12);
  __syncthreads();

  zero_acc(acc);
  gemm48<128, SY>(shY2, W13t, wave, lane, acc);

  float* shM = (float*)shA;   // bytes [0,24576) — does not overlap Y2
  const int g = lane >> 4, q = lane & 15;
#pragma unroll
  for (int c = 0; c < 2; ++c) {
    const int col = wave * 32 + c * 16 + q;
    const float bv = b13[col];
#pragma unroll
    for (int rt = 0; rt < 3; ++rt)
#pragma unroll
      for (int r = 0; r < 4; ++r)
        shM[(rt * 16 + g * 4 + r) * 128 + col] = acc[rt][c][r] + bv;
  }
  __syncthreads();

  const float* heb = hE_src + (size_t)bid * 6144;
  float* hob = hE_out + (size_t)bid * 6144;
#pragma unroll 1
  for (int i = 0; i < 12; ++i) {
    const int row = wave * 12 + i;
    float x0 = heb[row * 128 + lane]      + shM[row * 128 + lane];
    float x1 = heb[row * 128 + 64 + lane] + shM[row * 128 + 64 + lane];
    float s = x0 + x1, ss = x0 * x0 + x1 * x1;
#pragma unroll
    for (int off = 32; off; off >>= 1) { s += __shfl_xor(s, off); ss += __shfl_xor(ss, off); }
    const float mu = s * (1.f / 128.f);
    const float rs = rsqrtf(ss * (1.f / 128.f) - mu * mu + 1e-5f);
    hob[row * 128 + lane]      = g3[lane]      * (x0 - mu) * rs + be3[lane];
    hob[row * 128 + 64 + lane] = g3[lane + 64] * (x1 - mu) * rs + be3[lane + 64];
  }
}

extern "C" void kernel_launch(void* const* d_in, const int* in_sizes, int n_in,
                              void* d_out, int out_size, void* d_ws, size_t ws_size,
                              hipStream_t stream) {
  const float* h_V      = (const float*)d_in[0];
  const float* h_E      = (const float*)d_in[1];
  const int*   E_idx    = (const int*)d_in[2];
  const float* mask_V   = (const float*)d_in[3];
  const float* mask_att = (const float*)d_in[4];
  const float* W1   = (const float*)d_in[5];   const float* b1   = (const float*)d_in[6];
  const float* W2   = (const float*)d_in[7];   const float* b2   = (const float*)d_in[8];
  const float* W3   = (const float*)d_in[9];   const float* b3   = (const float*)d_in[10];
  const float* W11  = (const float*)d_in[11];  const float* b11  = (const float*)d_in[12];
  const float* W12  = (const float*)d_in[13];  const float* b12  = (const float*)d_in[14];
  const float* W13  = (const float*)d_in[15];  const float* b13  = (const float*)d_in[16];
  const float* Win  = (const float*)d_in[17];  const float* binp = (const float*)d_in[18];
  const float* Wout = (const float*)d_in[19];  const float* boutp= (const float*)d_in[20];
  const float* g1   = (const float*)d_in[21];  const float* be1  = (const float*)d_in[22];
  const float* g2   = (const float*)d_in[23];  const float* be2  = (const float*)d_in[24];
  const float* g3   = (const float*)d_in[25];  const float* be3  = (const float*)d_in[26];

  float* outV = (float*)d_out;                 // [2,1024,128]
  float* outE = outV + (size_t)BB * NN * HH;   // [2,1024,48,128]

  u16* ws    = (u16*)d_ws;
  u16* W1t   = ws;
  u16* W2t   = W1t  + 3 * 128 * 384;
  u16* W3t   = W2t  + 3 * 128 * 128;
  u16* W11t  = W3t  + 3 * 128 * 128;
  u16* W12t  = W11t + 3 * 128 * 384;
  u16* W13t  = W12t + 3 * 128 * 128;
  u16* Wint  = W13t + 3 * 128 * 128;
  u16* Woutt = Wint + 3 * 512 * 128;
  u16* hv0bf = Woutt + 3 * 128 * 512;
  u16* Pbf   = hv0bf + BB * NN * HH;
  u16* Qbf   = Pbf   + BB * NN * HH;
  float* Pf  = (float*)(Qbf + BB * NN * HH);
  float* Qf  = Pf + BB * NN * HH;

  conv_weights<<<512, 256, 0, stream>>>(W1, W2, W3, W11, W12, W13, Win, Wout, h_V,
                                        W1t, W2t, W3t, W11t, W12t, W13t, Wint, Woutt, hv0bf);

  for (int l = 0; l < LL; ++l) {
    const float* hv_res  = (l == 0) ? h_V : Qf;
    const u16*   hvbf_in = (l == 0) ? hv0bf : Qbf;
    const float* hE_src  = (l == 0) ? h_E : outE;
    float*       hv2_dst = (l == 2) ? outV : Qf;

    node_msg<<<BB * NN, 256, 0, stream>>>(
        hv_res, hvbf_in, hE_src, E_idx, mask_att,
        W1t + l * 128 * 384, W2t + l * 128 * 128, W3t + l * 128 * 128,
        b1 + l * 128, b2 + l * 128, b3 + l * 128,
        g1 + l * 128, be1 + l * 128,
        Pf, Pbf);

    ffn_kernel<<<(BB * NN) / 16, 256, 0, stream>>>(
        Pf, Pbf,
        Wint + l * 512 * 128, binp + l * 512,
        Woutt + l * 128 * 512, boutp + l * 128,
        g2 + l * 128, be2 + l * 128, mask_V,
        hv2_dst, Qbf);

    edge_kernel<<<BB * NN, 256, 0, stream>>>(
        Qbf, hE_src, E_idx,
        W11t + l * 128 * 384, W12t + l * 128 * 128, W13t + l * 128 * 128,
        b11 + l * 128, b12 + l * 128, b13 + l * 128,
        g3 + l * 128, be3 + l * 128,
        outE);
  }
}

// Round 3
// 376.236 us; speedup vs baseline: 2.7660x; 1.3266x over previous
//
#include <hip/hip_runtime.h>
#include <hip/hip_bf16.h>
#include <math.h>

#define BB 2
#define NN 1024
#define KK 48
#define HH 128
#define LL 3
#define SA 392   // A-tile row stride (bf16 elems): 384+8; rows 16B-aligned (784B)
#define SH 520   // FFN hidden row stride: 512+8
#define SX 136   // FFN input row stride

typedef __attribute__((ext_vector_type(8))) short s8v;   // 8 bf16
typedef __attribute__((ext_vector_type(4))) float f4v;   // MFMA acc
typedef unsigned short u16;

static __device__ __forceinline__ u16 f2bf(float x) {
  union { float f; unsigned u; } v; v.f = x;
  unsigned r = v.u + 0x7FFFu + ((v.u >> 16) & 1u);  // RNE
  return (u16)(r >> 16);
}
// fast tanh-form GELU: max |err| vs exact-erf gelu ~3e-3 (absorbed by bf16 threshold)
static __device__ __forceinline__ float geluf(float x) {
  float x2 = x * x;
  float u2 = x * (1.5957691216f + 0.0713548163f * x2);   // 2*sqrt(2/pi)*(x+0.044715x^3)
  float e = __expf(u2);
  float d = __builtin_amdgcn_rcpf(e + 1.0f);
  return x - x * d;   // 0.5*x*(1+tanh(u))
}

// 48xKD (LDS, row stride SAe) @ Wt[128][KD] (global, L2-hot).
template<int KD, int SAe>
static __device__ __forceinline__ void gemm48(const u16* __restrict__ A,
                                              const u16* __restrict__ Wt,
                                              int wave, int lane, f4v acc[3][2]) {
  const int g = lane >> 4, q = lane & 15;
  constexpr int NT = KD / 32;
  s8v B0[NT], B1[NT];
  const u16* wb0 = Wt + (wave * 32 + q) * KD + g * 8;
  const u16* wb1 = wb0 + 16 * KD;
#pragma unroll
  for (int t = 0; t < NT; ++t) {
    B0[t] = *(const s8v*)(wb0 + t * 32);
    B1[t] = *(const s8v*)(wb1 + t * 32);
  }
#pragma unroll
  for (int t = 0; t < NT; ++t) {
    const u16* Ab = A + t * 32 + g * 8;
    s8v a0 = *(const s8v*)(Ab + q * SAe);
    s8v a1 = *(const s8v*)(Ab + (16 + q) * SAe);
    s8v a2 = *(const s8v*)(Ab + (32 + q) * SAe);
    acc[0][0] = __builtin_amdgcn_mfma_f32_16x16x32_bf16(a0, B0[t], acc[0][0], 0, 0, 0);
    acc[0][1] = __builtin_amdgcn_mfma_f32_16x16x32_bf16(a0, B1[t], acc[0][1], 0, 0, 0);
    acc[1][0] = __builtin_amdgcn_mfma_f32_16x16x32_bf16(a1, B0[t], acc[1][0], 0, 0, 0);
    acc[1][1] = __builtin_amdgcn_mfma_f32_16x16x32_bf16(a1, B1[t], acc[1][1], 0, 0, 0);
    acc[2][0] = __builtin_amdgcn_mfma_f32_16x16x32_bf16(a2, B0[t], acc[2][0], 0, 0, 0);
    acc[2][1] = __builtin_amdgcn_mfma_f32_16x16x32_bf16(a2, B1[t], acc[2][1], 0, 0, 0);
  }
}

static __device__ __forceinline__ void zero_acc(f4v acc[3][2]) {
#pragma unroll
  for (int rt = 0; rt < 3; ++rt)
#pragma unroll
    for (int c = 0; c < 2; ++c) acc[rt][c] = (f4v){0.f, 0.f, 0.f, 0.f};
}

// acc(+bias, gelu) -> LDS Y bf16 (row stride SYe). C layout: col=lane&15, row=(lane>>4)*4+r.
template<int SYe>
static __device__ __forceinline__ void store_act(const f4v acc[3][2], u16* __restrict__ Y,
                                                 int wave, int lane, const float* __restrict__ bias) {
  const int g = lane >> 4, q = lane & 15;
#pragma unroll
  for (int c = 0; c < 2; ++c) {
    const int col = wave * 32 + c * 16 + q;
    const float bv = bias[col];
#pragma unroll
    for (int rt = 0; rt < 3; ++rt)
#pragma unroll
      for (int r = 0; r < 4; ++r) {
        const int row = rt * 16 + g * 4 + r;
        Y[row * SYe + col] = f2bf(geluf(acc[rt][c][r] + bv));
      }
  }
}

// Staging: A = [hv_self(bf16 copy) | h_E(f32->bf16) | hv_gather(bf16 copy)]
static __device__ __forceinline__ void stage_A(u16* __restrict__ shA, const u16* __restrict__ hvbf,
                                               const float* __restrict__ hE_src,
                                               const int* __restrict__ eidx,
                                               int bid, int bbase, int tid) {
  const uint4* hvb = (const uint4*)(hvbf + (size_t)bid * 128);
#pragma unroll
  for (int p = 0; p < 3; ++p) {
    int i = tid + p * 256; int row = i >> 4, c = i & 15;
    *(uint4*)(shA + row * SA + c * 8) = hvb[c];
  }
  const float4* hEr = (const float4*)(hE_src + (size_t)bid * 6144);
#pragma unroll
  for (int p = 0; p < 6; ++p) {
    int i = tid + p * 256; int row = i >> 5, c = i & 31;
    float4 v = hEr[row * 32 + c];
    uint2 pk;
    pk.x = (unsigned)f2bf(v.x) | ((unsigned)f2bf(v.y) << 16);
    pk.y = (unsigned)f2bf(v.z) | ((unsigned)f2bf(v.w) << 16);
    *(uint2*)(shA + row * SA + 128 + c * 4) = pk;
  }
#pragma unroll
  for (int p = 0; p < 3; ++p) {
    int i = tid + p * 256; int row = i >> 4, c = i & 15;
    const int idx = eidx[bid * 48 + row];                 // L1-hot broadcast
    const uint4* src = (const uint4*)(hvbf + (size_t)(bbase + idx) * 128);
    *(uint4*)(shA + row * SA + 256 + c * 8) = src[c];
  }
}

// ---------------- weight/hv convert ----------------
__global__ void conv_weights(const float* __restrict__ W1, const float* __restrict__ W2,
                             const float* __restrict__ W3, const float* __restrict__ W11,
                             const float* __restrict__ W12, const float* __restrict__ W13,
                             const float* __restrict__ Win, const float* __restrict__ Wout,
                             const float* __restrict__ hV,
                             u16* __restrict__ W1t, u16* __restrict__ W2t,
                             u16* __restrict__ W3t, u16* __restrict__ W11t,
                             u16* __restrict__ W12t, u16* __restrict__ W13t,
                             u16* __restrict__ Wint, u16* __restrict__ Woutt,
                             u16* __restrict__ hv0bf) {
  const int tid = blockIdx.x * blockDim.x + threadIdx.x;
  const int nt = gridDim.x * blockDim.x;
  for (int i = tid; i < LL * 384 * 128; i += nt) {
    int l = i / (384 * 128), rem = i - l * 384 * 128;
    int k = rem / 128, n = rem - k * 128;
    W1t [(l * 128 + n) * 384 + k] = f2bf(W1[i]);
    W11t[(l * 128 + n) * 384 + k] = f2bf(W11[i]);
  }
  for (int i = tid; i < LL * 128 * 128; i += nt) {
    int l = i / (128 * 128), rem = i - l * 128 * 128;
    int k = rem / 128, n = rem - k * 128;
    W2t [(l * 128 + n) * 128 + k] = f2bf(W2[i]);
    W3t [(l * 128 + n) * 128 + k] = f2bf(W3[i]);
    W12t[(l * 128 + n) * 128 + k] = f2bf(W12[i]);
    W13t[(l * 128 + n) * 128 + k] = f2bf(W13[i]);
  }
  for (int i = tid; i < LL * 128 * 512; i += nt) {
    int l = i / (128 * 512), rem = i - l * 128 * 512;
    int k = rem / 512, u = rem - k * 512;
    Wint[(l * 512 + u) * 128 + k] = f2bf(Win[i]);
  }
  for (int i = tid; i < LL * 512 * 128; i += nt) {
    int l = i / (512 * 128), rem = i - l * 512 * 128;
    int k = rem / 128, n = rem - k * 128;
    Woutt[(l * 128 + n) * 512 + k] = f2bf(Wout[i]);
  }
  for (int i = tid; i < BB * NN * HH; i += nt) hv0bf[i] = f2bf(hV[i]);
}

// ---------------- node message: MLP + masked aggregate + LN1 ----------------
__global__ __launch_bounds__(256, 4) void node_msg(
    const float* __restrict__ hv_res, const u16* __restrict__ hvbf,
    const float* __restrict__ hE_src, const int* __restrict__ eidx,
    const float* __restrict__ mask_att,
    const u16* __restrict__ W1t, const u16* __restrict__ W2t, const u16* __restrict__ W3t,
    const float* __restrict__ b1, const float* __restrict__ b2, const float* __restrict__ b3,
    const float* __restrict__ g1, const float* __restrict__ be1,
    float* __restrict__ hv1, u16* __restrict__ hv1bf) {
  __shared__ __align__(16) u16 shA[48 * SA];   // Y1 -> cols[0,128), Y2 -> cols[256,384)
  __shared__ float sh_mask[48];
  __shared__ float sh_x[128];
  __shared__ float sh_st[2];

  const int tid = threadIdx.x, lane = tid & 63, wave = tid >> 6;
  const int bid = blockIdx.x, bbase = bid & ~(NN - 1);

  if (tid < 48) sh_mask[tid] = mask_att[bid * 48 + tid];
  stage_A(shA, hvbf, hE_src, eidx, bid, bbase, tid);
  __syncthreads();

  f4v acc[3][2];
  zero_acc(acc);
  gemm48<384, SA>(shA, W1t, wave, lane, acc);
  __syncthreads();                       // all waves done reading A before Y1 overwrite
  store_act<SA>(acc, shA, wave, lane, b1);        // Y1 = cols[0,128)
  __syncthreads();

  zero_acc(acc);
  gemm48<128, SA>(shA, W2t, wave, lane, acc);
  store_act<SA>(acc, shA + 256, wave, lane, b2);  // Y2 = cols[256,384), dead since gemm1
  __syncthreads();

  zero_acc(acc);
  gemm48<128, SA>(shA + 256, W3t, wave, lane, acc);

  const int g = lane >> 4, q = lane & 15;
  float msum = 0.f;
#pragma unroll
  for (int k = 0; k < 48; ++k) msum += sh_mask[k];
  float p0 = 0.f, p1 = 0.f;
#pragma unroll
  for (int rt = 0; rt < 3; ++rt)
#pragma unroll
    for (int r = 0; r < 4; ++r) {
      const int row = rt * 16 + g * 4 + r;
      const float mk = sh_mask[row];
      p0 += acc[rt][0][r] * mk;
      p1 += acc[rt][1][r] * mk;
    }
  p0 += __shfl_xor(p0, 16); p0 += __shfl_xor(p0, 32);
  p1 += __shfl_xor(p1, 16); p1 += __shfl_xor(p1, 32);
  if (g == 0) {
    const int c0 = wave * 32 + q, c1 = wave * 32 + 16 + q;
    sh_x[c0] = hv_res[(size_t)bid * 128 + c0] + (p0 + b3[c0] * msum) * (1.f / 30.f);
    sh_x[c1] = hv_res[(size_t)bid * 128 + c1] + (p1 + b3[c1] * msum) * (1.f / 30.f);
  }
  __syncthreads();

  if (tid < 64) {
    float a = sh_x[tid], c2 = sh_x[tid + 64];
    float s = a + c2, ss = a * a + c2 * c2;
#pragma unroll
    for (int off = 32; off; off >>= 1) { s += __shfl_xor(s, off); ss += __shfl_xor(ss, off); }
    if (tid == 0) { float mu = s * (1.f / 128.f); sh_st[0] = mu; sh_st[1] = ss * (1.f / 128.f) - mu * mu; }
  }
  __syncthreads();
  if (tid < 128) {
    float mu = sh_st[0], rs = rsqrtf(sh_st[1] + 1e-5f);
    float v = g1[tid] * (sh_x[tid] - mu) * rs + be1[tid];
    hv1[(size_t)bid * 128 + tid] = v;
    hv1bf[(size_t)bid * 128 + tid] = f2bf(v);
  }
}

// ---------------- FFN: 8 rows/block (256 blocks), 128->512(gelu)->128, LN2, mask ----------------
__global__ __launch_bounds__(256) void ffn_kernel(
    const float* __restrict__ hv1, const u16* __restrict__ hv1bf,
    const u16* __restrict__ Wint, const float* __restrict__ binp,
    const u16* __restrict__ Woutt, const float* __restrict__ boutp,
    const float* __restrict__ g2, const float* __restrict__ be2,
    const float* __restrict__ mask_V,
    float* __restrict__ hv2, u16* __restrict__ hv2bf) {
  __shared__ __align__(16) u16 shX[16 * SX];
  __shared__ __align__(16) u16 shH[16 * SH];
  __shared__ float shM[8 * 128];
  const int tid = threadIdx.x, lane = tid & 63, wave = tid >> 6;
  const int g = lane >> 4, q = lane & 15;
  const int r0 = blockIdx.x * 8;

  {
    int row = tid >> 4, c = tid & 15;
    uint4 v = (uint4){0, 0, 0, 0};
    if (tid < 128) v = ((const uint4*)(hv1bf + (size_t)r0 * 128))[tid];
    *(uint4*)(shX + row * SX + c * 8) = v;
  }
  __syncthreads();

  s8v a[4];
#pragma unroll
  for (int t = 0; t < 4; ++t) a[t] = *(const s8v*)(shX + q * SX + t * 32 + g * 8);
#pragma unroll
  for (int cf = 0; cf < 8; ++cf) {
    const int u = wave * 128 + cf * 16 + q;
    const u16* wb = Wint + (size_t)u * 128 + g * 8;
    f4v acc = (f4v){0.f, 0.f, 0.f, 0.f};
#pragma unroll
    for (int t = 0; t < 4; ++t)
      acc = __builtin_amdgcn_mfma_f32_16x16x32_bf16(a[t], *(const s8v*)(wb + t * 32), acc, 0, 0, 0);
    const float bv = binp[u];
#pragma unroll
    for (int r = 0; r < 4; ++r) shH[(g * 4 + r) * SH + u] = f2bf(geluf(acc[r] + bv));
  }
  __syncthreads();

#pragma unroll
  for (int c = 0; c < 2; ++c) {
    const int col = wave * 32 + c * 16 + q;
    const u16* wb = Woutt + (size_t)col * 512 + g * 8;
    s8v Bv[16];
#pragma unroll
    for (int t = 0; t < 16; ++t) Bv[t] = *(const s8v*)(wb + t * 32);
    f4v acc = (f4v){0.f, 0.f, 0.f, 0.f};
#pragma unroll
    for (int t = 0; t < 16; ++t) {
      s8v av = *(const s8v*)(shH + q * SH + t * 32 + g * 8);
      acc = __builtin_amdgcn_mfma_f32_16x16x32_bf16(av, Bv[t], acc, 0, 0, 0);
    }
    const float bv = boutp[col];
#pragma unroll
    for (int r = 0; r < 4; ++r) {
      const int row = g * 4 + r;
      if (row < 8) shM[row * 128 + col] = acc[r] + bv;
    }
  }
  __syncthreads();

#pragma unroll
  for (int i = 0; i < 2; ++i) {
    const int row = wave * 2 + i, gr = r0 + row;
    float x0 = hv1[(size_t)gr * 128 + lane]      + shM[row * 128 + lane];
    float x1 = hv1[(size_t)gr * 128 + 64 + lane] + shM[row * 128 + 64 + lane];
    float s = x0 + x1, ss = x0 * x0 + x1 * x1;
#pragma unroll
    for (int off = 32; off; off >>= 1) { s += __shfl_xor(s, off); ss += __shfl_xor(ss, off); }
    const float mu = s * (1.f / 128.f);
    const float rs = rsqrtf(ss * (1.f / 128.f) - mu * mu + 1e-5f);
    const float mv = mask_V[gr];
    float o0 = mv * (g2[lane]      * (x0 - mu) * rs + be2[lane]);
    float o1 = mv * (g2[lane + 64] * (x1 - mu) * rs + be2[lane + 64]);
    hv2[(size_t)gr * 128 + lane] = o0;
    hv2[(size_t)gr * 128 + 64 + lane] = o1;
    hv2bf[(size_t)gr * 128 + lane] = f2bf(o0);
    hv2bf[(size_t)gr * 128 + 64 + lane] = f2bf(o1);
  }
}

// ---------------- edge update: MLP + LN3 ----------------
__global__ __launch_bounds__(256, 4) void edge_kernel(
    const u16* __restrict__ hvbf, const float* __restrict__ hE_src,
    const int* __restrict__ eidx,
    const u16* __restrict__ W11t, const u16* __restrict__ W12t, const u16* __restrict__ W13t,
    const float* __restrict__ b11, const float* __restrict__ b12, const float* __restrict__ b13,
    const float* __restrict__ g3, const float* __restrict__ be3,
    float* __restrict__ hE_out) {
  __shared__ __align__(16) u16 shA[48 * SA];   // Y1->cols[0,128), Y2->cols[256,384), M split over both

  const int tid = threadIdx.x, lane = tid & 63, wave = tid >> 6;
  const int bid = blockIdx.x, bbase = bid & ~(NN - 1);

  stage_A(shA, hvbf, hE_src, eidx, bid, bbase, tid);
  __syncthreads();

  f4v acc[3][2];
  zero_acc(acc);
  gemm48<384, SA>(shA, W11t, wave, lane, acc);
  __syncthreads();
  store_act<SA>(acc, shA, wave, lane, b11);
  __syncthreads();

  zero_acc(acc);
  gemm48<128, SA>(shA, W12t, wave, lane, acc);
  store_act<SA>(acc, shA + 256, wave, lane, b12);
  __syncthreads();

  zero_acc(acc);
  gemm48<128, SA>(shA + 256, W13t, wave, lane, acc);
  __syncthreads();                       // all Y2 reads done before M overwrites

  // M (f32): col<64 -> f32[row*196+col] (Y1 region), col>=64 -> f32[row*196+64+col] (Y2 region)
  float* shMf = (float*)shA;
  const int g = lane >> 4, q = lane & 15;
#pragma unroll
  for (int c = 0; c < 2; ++c) {
    const int col = wave * 32 + c * 16 + q;
    const int cofs = (col >= 64) ? (64 + col) : col;   // wave-uniform branch
    const float bv = b13[col];
#pragma unroll
    for (int rt = 0; rt < 3; ++rt)
#pragma unroll
      for (int r = 0; r < 4; ++r)
        shMf[(rt * 16 + g * 4 + r) * 196 + cofs] = acc[rt][c][r] + bv;
  }
  __syncthreads();

  const float* heb = hE_src + (size_t)bid * 6144;
  float* hob = hE_out + (size_t)bid * 6144;
#pragma unroll 1
  for (int i = 0; i < 12; ++i) {
    const int row = wave * 12 + i;
    float x0 = heb[row * 128 + lane]      + shMf[row * 196 + lane];
    float x1 = heb[row * 128 + 64 + lane] + shMf[row * 196 + 128 + lane];
    float s = x0 + x1, ss = x0 * x0 + x1 * x1;
#pragma unroll
    for (int off = 32; off; off >>= 1) { s += __shfl_xor(s, off); ss += __shfl_xor(ss, off); }
    const float mu = s * (1.f / 128.f);
    const float rs = rsqrtf(ss * (1.f / 128.f) - mu * mu + 1e-5f);
    hob[row * 128 + lane]      = g3[lane]      * (x0 - mu) * rs + be3[lane];
    hob[row * 128 + 64 + lane] = g3[lane + 64] * (x1 - mu) * rs + be3[lane + 64];
  }
}

extern "C" void kernel_launch(void* const* d_in, const int* in_sizes, int n_in,
                              void* d_out, int out_size, void* d_ws, size_t ws_size,
                              hipStream_t stream) {
  const float* h_V      = (const float*)d_in[0];
  const float* h_E      = (const float*)d_in[1];
  const int*   E_idx    = (const int*)d_in[2];
  const float* mask_V   = (const float*)d_in[3];
  const float* mask_att = (const float*)d_in[4];
  const float* W1   = (const float*)d_in[5];   const float* b1   = (const float*)d_in[6];
  const float* W2   = (const float*)d_in[7];   const float* b2   = (const float*)d_in[8];
  const float* W3   = (const float*)d_in[9];   const float* b3   = (const float*)d_in[10];
  const float* W11  = (const float*)d_in[11];  const float* b11  = (const float*)d_in[12];
  const float* W12  = (const float*)d_in[13];  const float* b12  = (const float*)d_in[14];
  const float* W13  = (const float*)d_in[15];  const float* b13  = (const float*)d_in[16];
  const float* Win  = (const float*)d_in[17];  const float* binp = (const float*)d_in[18];
  const float* Wout = (const float*)d_in[19];  const float* boutp= (const float*)d_in[20];
  const float* g1   = (const float*)d_in[21];  const float* be1  = (const float*)d_in[22];
  const float* g2   = (const float*)d_in[23];  const float* be2  = (const float*)d_in[24];
  const float* g3   = (const float*)d_in[25];  const float* be3  = (const float*)d_in[26];

  float* outV = (float*)d_out;                 // [2,1024,128]
  float* outE = outV + (size_t)BB * NN * HH;   // [2,1024,48,128]

  u16* ws    = (u16*)d_ws;
  u16* W1t   = ws;
  u16* W2t   = W1t  + 3 * 128 * 384;
  u16* W3t   = W2t  + 3 * 128 * 128;
  u16* W11t  = W3t  + 3 * 128 * 128;
  u16* W12t  = W11t + 3 * 128 * 384;
  u16* W13t  = W12t + 3 * 128 * 128;
  u16* Wint  = W13t + 3 * 128 * 128;
  u16* Woutt = Wint + 3 * 512 * 128;
  u16* hv0bf = Woutt + 3 * 128 * 512;
  u16* Pbf   = hv0bf + BB * NN * HH;
  u16* Qbf   = Pbf   + BB * NN * HH;
  float* Pf  = (float*)(Qbf + BB * NN * HH);
  float* Qf  = Pf + BB * NN * HH;

  conv_weights<<<512, 256, 0, stream>>>(W1, W2, W3, W11, W12, W13, Win, Wout, h_V,
                                        W1t, W2t, W3t, W11t, W12t, W13t, Wint, Woutt, hv0bf);

  for (int l = 0; l < LL; ++l) {
    const float* hv_res  = (l == 0) ? h_V : Qf;
    const u16*   hvbf_in = (l == 0) ? hv0bf : Qbf;
    const float* hE_src  = (l == 0) ? h_E : outE;
    float*       hv2_dst = (l == 2) ? outV : Qf;

    node_msg<<<BB * NN, 256, 0, stream>>>(
        hv_res, hvbf_in, hE_src, E_idx, mask_att,
        W1t + l * 128 * 384, W2t + l * 128 * 128, W3t + l * 128 * 128,
        b1 + l * 128, b2 + l * 128, b3 + l * 128,
        g1 + l * 128, be1 + l * 128,
        Pf, Pbf);

    ffn_kernel<<<(BB * NN) / 8, 256, 0, stream>>>(
        Pf, Pbf,
        Wint + l * 512 * 128, binp + l * 512,
        Woutt + l * 128 * 512, boutp + l * 128,
        g2 + l * 128, be2 + l * 128, mask_V,
        hv2_dst, Qbf);

    edge_kernel<<<BB * NN, 256, 0, stream>>>(
        Qbf, hE_src, E_idx,
        W11t + l * 128 * 384, W12t + l * 128 * 128, W13t + l * 128 * 128,
        b11 + l * 128, b12 + l * 128, b13 + l * 128,
        g3 + l * 128, be3 + l * 128,
        outE);
  }
}

// Round 4
// 326.164 us; speedup vs baseline: 3.1906x; 1.1535x over previous
//
#include <hip/hip_runtime.h>
#include <hip/hip_bf16.h>
#include <math.h>

#define BB 2
#define NN 1024
#define HH 128
#define LL 3
#define SY 136   // LDS tile row stride (bf16 elems): 128+8
#define SH 520   // FFN hidden row stride
#define SX 136   // FFN input row stride
#define SM 132   // edge M f32 row stride

typedef __attribute__((ext_vector_type(8))) short s8v;   // 8 bf16
typedef __attribute__((ext_vector_type(4))) float f4v;   // MFMA acc
typedef unsigned short u16;

static __device__ __forceinline__ u16 f2bf(float x) {
  union { float f; unsigned u; } v; v.f = x;
  unsigned r = v.u + 0x7FFFu + ((v.u >> 16) & 1u);  // RNE
  return (u16)(r >> 16);
}
// fast tanh-form GELU (|err| vs erf-gelu ~3e-3)
static __device__ __forceinline__ float geluf(float x) {
  float x2 = x * x;
  float u2 = x * (1.5957691216f + 0.0713548163f * x2);
  float e = __expf(u2);
  float d = __builtin_amdgcn_rcpf(e + 1.0f);
  return x - x * d;
}

// 48x128 (LDS, stride SY) @ Wt[128][128] (L2-hot). acc pre-initialized by caller.
static __device__ __forceinline__ void gemm48k128(const u16* __restrict__ A,
                                                  const u16* __restrict__ Wt,
                                                  int wave, int lane, f4v acc[3][2]) {
  const int g = lane >> 4, q = lane & 15;
  s8v B0[4], B1[4];
  const u16* wb0 = Wt + (wave * 32 + q) * 128 + g * 8;
  const u16* wb1 = wb0 + 16 * 128;
#pragma unroll
  for (int t = 0; t < 4; ++t) { B0[t] = *(const s8v*)(wb0 + t * 32); B1[t] = *(const s8v*)(wb1 + t * 32); }
#pragma unroll
  for (int t = 0; t < 4; ++t) {
    const u16* Ab = A + t * 32 + g * 8;
    s8v a0 = *(const s8v*)(Ab + q * SY);
    s8v a1 = *(const s8v*)(Ab + (16 + q) * SY);
    s8v a2 = *(const s8v*)(Ab + (32 + q) * SY);
    acc[0][0] = __builtin_amdgcn_mfma_f32_16x16x32_bf16(a0, B0[t], acc[0][0], 0, 0, 0);
    acc[0][1] = __builtin_amdgcn_mfma_f32_16x16x32_bf16(a0, B1[t], acc[0][1], 0, 0, 0);
    acc[1][0] = __builtin_amdgcn_mfma_f32_16x16x32_bf16(a1, B0[t], acc[1][0], 0, 0, 0);
    acc[1][1] = __builtin_amdgcn_mfma_f32_16x16x32_bf16(a1, B1[t], acc[1][1], 0, 0, 0);
    acc[2][0] = __builtin_amdgcn_mfma_f32_16x16x32_bf16(a2, B0[t], acc[2][0], 0, 0, 0);
    acc[2][1] = __builtin_amdgcn_mfma_f32_16x16x32_bf16(a2, B1[t], acc[2][1], 0, 0, 0);
  }
}

static __device__ __forceinline__ void zero_acc(f4v acc[3][2]) {
#pragma unroll
  for (int rt = 0; rt < 3; ++rt)
#pragma unroll
    for (int c = 0; c < 2; ++c) acc[rt][c] = (f4v){0.f, 0.f, 0.f, 0.f};
}

// acc(+bias, gelu) -> LDS Y bf16 (stride SY). C layout: col=lane&15, row=(lane>>4)*4+r.
static __device__ __forceinline__ void store_act(const f4v acc[3][2], u16* __restrict__ Y,
                                                 int wave, int lane, const float* __restrict__ bias) {
  const int g = lane >> 4, q = lane & 15;
#pragma unroll
  for (int c = 0; c < 2; ++c) {
    const int col = wave * 32 + c * 16 + q;
    const float bv = bias[col];
#pragma unroll
    for (int rt = 0; rt < 3; ++rt)
#pragma unroll
      for (int r = 0; r < 4; ++r) {
        const int row = rt * 16 + g * 4 + r;
        Y[row * SY + col] = f2bf(geluf(acc[rt][c][r] + bv));
      }
  }
}

// stage hE (48x128 f32 -> bf16 LDS)
static __device__ __forceinline__ void stage_hE(u16* __restrict__ dst, const float* __restrict__ src,
                                                int tid) {
  const float4* hEr = (const float4*)src;
#pragma unroll
  for (int p = 0; p < 6; ++p) {
    int i = tid + p * 256; int row = i >> 5, c = i & 31;
    float4 v = hEr[row * 32 + c];
    uint2 pk;
    pk.x = (unsigned)f2bf(v.x) | ((unsigned)f2bf(v.y) << 16);
    pk.y = (unsigned)f2bf(v.z) | ((unsigned)f2bf(v.w) << 16);
    *(uint2*)(dst + row * SY + c * 4) = pk;
  }
}

// ---------------- weight/hv convert ----------------
// PRE_l layout [512][128] bf16: rows 0-127 W11aT(l), 128-255 W11cT(l),
//                               256-383 W1aT((l+1)%3), 384-511 W1cT((l+1)%3)
__global__ void conv_weights(const float* __restrict__ W1, const float* __restrict__ W2,
                             const float* __restrict__ W3, const float* __restrict__ W11,
                             const float* __restrict__ W12, const float* __restrict__ W13,
                             const float* __restrict__ Win, const float* __restrict__ Wout,
                             const float* __restrict__ hV,
                             u16* __restrict__ W1bT, u16* __restrict__ W2t,
                             u16* __restrict__ W3t, u16* __restrict__ W11bT,
                             u16* __restrict__ W12t, u16* __restrict__ W13t,
                             u16* __restrict__ Wint, u16* __restrict__ Woutt,
                             u16* __restrict__ PRE, u16* __restrict__ hv0bf) {
  const int tid = blockIdx.x * blockDim.x + threadIdx.x;
  const int nt = gridDim.x * blockDim.x;
  for (int i = tid; i < LL * 128 * 128; i += nt) {
    int l = i >> 14, rem = i & 16383;
    int k = rem >> 7, n = rem & 127;
    const int o = (l * 128 + n) * 128 + k;
    W1bT [o] = f2bf(W1 [l * 49152 + (128 + k) * 128 + n]);
    W11bT[o] = f2bf(W11[l * 49152 + (128 + k) * 128 + n]);
    W2t  [o] = f2bf(W2 [i]);   // W2[l][k][n] -> [l][n][k]
    W3t  [o] = f2bf(W3 [i]);
    W12t [o] = f2bf(W12[i]);
    W13t [o] = f2bf(W13[i]);
    // wait: W2t needs transpose: W2t[(l*128+n)*128+k] = W2[l*16384 + k*128 + n]
  }
  // redo transposed 128x128s correctly (overwrite above partial-transpose writes)
  for (int i = tid; i < LL * 128 * 128; i += nt) {
    int l = i >> 14, rem = i & 16383;
    int k = rem >> 7, n = rem & 127;
    const int o = (l * 128 + n) * 128 + k;
    const int s = l * 16384 + k * 128 + n;
    W2t [o] = f2bf(W2 [s]);
    W3t [o] = f2bf(W3 [s]);
    W12t[o] = f2bf(W12[s]);
    W13t[o] = f2bf(W13[s]);
    const int ln = (l + 1 == LL) ? 0 : l + 1;
    PRE[l * 65536 + (0 * 128 + n) * 128 + k] = f2bf(W11[l * 49152 + k * 128 + n]);
    PRE[l * 65536 + (1 * 128 + n) * 128 + k] = f2bf(W11[l * 49152 + (256 + k) * 128 + n]);
    PRE[l * 65536 + (2 * 128 + n) * 128 + k] = f2bf(W1 [ln * 49152 + k * 128 + n]);
    PRE[l * 65536 + (3 * 128 + n) * 128 + k] = f2bf(W1 [ln * 49152 + (256 + k) * 128 + n]);
  }
  for (int i = tid; i < LL * 128 * 512; i += nt) {
    int l = i / (128 * 512), rem = i - l * 128 * 512;
    int k = rem / 512, u = rem - k * 512;
    Wint[(l * 512 + u) * 128 + k] = f2bf(Win[i]);
  }
  for (int i = tid; i < LL * 512 * 128; i += nt) {
    int l = i / (512 * 128), rem = i - l * 512 * 128;
    int k = rem / 128, n = rem - k * 128;
    Woutt[(l * 128 + n) * 512 + k] = f2bf(Wout[i]);
  }
  for (int i = tid; i < BB * NN * HH; i += nt) hv0bf[i] = f2bf(hV[i]);
}

// ---------------- layer-0 node pre: Q = hv@W1a, P = hv@W1c ----------------
__global__ __launch_bounds__(256) void pre_kernel(const u16* __restrict__ hvbf,
                                                  const u16* __restrict__ Wq,
                                                  const u16* __restrict__ Wp,
                                                  float* __restrict__ Q, float* __restrict__ P) {
  __shared__ __align__(16) u16 shX[16 * SX];
  const int tid = threadIdx.x, lane = tid & 63, wave = tid >> 6;
  const int g = lane >> 4, q = lane & 15;
  const int r0 = blockIdx.x * 16;
  { int row = tid >> 4, c = tid & 15;
    *(uint4*)(shX + row * SX + c * 8) = ((const uint4*)(hvbf + (size_t)r0 * 128))[tid]; }
  __syncthreads();
  s8v af[4];
#pragma unroll
  for (int t = 0; t < 4; ++t) af[t] = *(const s8v*)(shX + q * SX + t * 32 + g * 8);
  const u16* W = (wave < 2) ? Wq : Wp;
  float* D = (wave < 2) ? Q : P;
  const int c0 = (wave & 1) * 64;
#pragma unroll
  for (int cf = 0; cf < 4; ++cf) {
    const int col = c0 + cf * 16 + q;
    const u16* wb = W + (size_t)col * 128 + g * 8;
    f4v acc = (f4v){0.f, 0.f, 0.f, 0.f};
#pragma unroll
    for (int t = 0; t < 4; ++t)
      acc = __builtin_amdgcn_mfma_f32_16x16x32_bf16(af[t], *(const s8v*)(wb + t * 32), acc, 0, 0, 0);
#pragma unroll
    for (int r = 0; r < 4; ++r) D[(size_t)(r0 + g * 4 + r) * 128 + col] = acc[r];
  }
}

// ---------------- node message: init(Q,P-gather) + K=128 MLP + aggregate + LN1 ----------------
__global__ __launch_bounds__(256, 6) void node_msg(
    const float* __restrict__ hv_res, const float* __restrict__ Qn, const float* __restrict__ Pn,
    const float* __restrict__ hE_src, const int* __restrict__ eidx,
    const float* __restrict__ mask_att,
    const u16* __restrict__ W1bT, const u16* __restrict__ W2t, const u16* __restrict__ W3t,
    const float* __restrict__ b1, const float* __restrict__ b2, const float* __restrict__ b3,
    const float* __restrict__ g1, const float* __restrict__ be1,
    float* __restrict__ hv1, u16* __restrict__ hv1bf) {
  __shared__ __align__(16) u16 buf[2 * 48 * SY];
  __shared__ float sh_mask[48];
  __shared__ int sh_idx[48];
  __shared__ float sh_x[128];
  __shared__ float sh_st[2];
  u16* bufA = buf;
  u16* bufB = buf + 48 * SY;

  const int tid = threadIdx.x, lane = tid & 63, wave = tid >> 6;
  const int g = lane >> 4, q = lane & 15;
  const int bid = blockIdx.x, bbase = bid & ~(NN - 1);

  if (tid < 48) { sh_idx[tid] = eidx[bid * 48 + tid]; sh_mask[tid] = mask_att[bid * 48 + tid]; }
  stage_hE(bufA, hE_src + (size_t)bid * 6144, tid);
  __syncthreads();

  f4v acc[3][2];
  {
    const float* Qr = Qn + (size_t)bid * 128;
#pragma unroll
    for (int c = 0; c < 2; ++c) {
      const int col = wave * 32 + c * 16 + q;
      const float qv = Qr[col];
#pragma unroll
      for (int rt = 0; rt < 3; ++rt)
#pragma unroll
        for (int r = 0; r < 4; ++r) {
          const int row = rt * 16 + g * 4 + r;
          acc[rt][c][r] = qv + Pn[(size_t)(bbase + sh_idx[row]) * 128 + col];
        }
    }
  }
  gemm48k128(bufA, W1bT, wave, lane, acc);
  store_act(acc, bufB, wave, lane, b1);
  __syncthreads();

  zero_acc(acc);
  gemm48k128(bufB, W2t, wave, lane, acc);
  store_act(acc, bufA, wave, lane, b2);
  __syncthreads();

  zero_acc(acc);
  gemm48k128(bufA, W3t, wave, lane, acc);

  float msum = 0.f;
#pragma unroll
  for (int k = 0; k < 48; ++k) msum += sh_mask[k];
  float p0 = 0.f, p1 = 0.f;
#pragma unroll
  for (int rt = 0; rt < 3; ++rt)
#pragma unroll
    for (int r = 0; r < 4; ++r) {
      const int row = rt * 16 + g * 4 + r;
      const float mk = sh_mask[row];
      p0 += acc[rt][0][r] * mk;
      p1 += acc[rt][1][r] * mk;
    }
  p0 += __shfl_xor(p0, 16); p0 += __shfl_xor(p0, 32);
  p1 += __shfl_xor(p1, 16); p1 += __shfl_xor(p1, 32);
  if (g == 0) {
    const int c0 = wave * 32 + q, c1 = wave * 32 + 16 + q;
    sh_x[c0] = hv_res[(size_t)bid * 128 + c0] + (p0 + b3[c0] * msum) * (1.f / 30.f);
    sh_x[c1] = hv_res[(size_t)bid * 128 + c1] + (p1 + b3[c1] * msum) * (1.f / 30.f);
  }
  __syncthreads();

  if (tid < 64) {
    float a = sh_x[tid], c2 = sh_x[tid + 64];
    float s = a + c2, ss = a * a + c2 * c2;
#pragma unroll
    for (int off = 32; off; off >>= 1) { s += __shfl_xor(s, off); ss += __shfl_xor(ss, off); }
    if (tid == 0) { float mu = s * (1.f / 128.f); sh_st[0] = mu; sh_st[1] = ss * (1.f / 128.f) - mu * mu; }
  }
  __syncthreads();
  if (tid < 128) {
    float mu = sh_st[0], rs = rsqrtf(sh_st[1] + 1e-5f);
    float v = g1[tid] * (sh_x[tid] - mu) * rs + be1[tid];
    hv1[(size_t)bid * 128 + tid] = v;
    hv1bf[(size_t)bid * 128 + tid] = f2bf(v);
  }
}

// ---------------- FFN + LN2 + mask + fused pre-products for edge(l) and node(l+1) ----------------
__global__ __launch_bounds__(256) void ffn_kernel(
    const float* __restrict__ hv1, const u16* __restrict__ hv1bf,
    const u16* __restrict__ Wint, const float* __restrict__ binp,
    const u16* __restrict__ Woutt, const float* __restrict__ boutp,
    const float* __restrict__ g2, const float* __restrict__ be2,
    const float* __restrict__ mask_V,
    const u16* __restrict__ PRE,
    float* __restrict__ hv2,
    float* __restrict__ Qe, float* __restrict__ Pe,
    float* __restrict__ QnN, float* __restrict__ PnN) {
  __shared__ __align__(16) u16 shX[16 * SX];
  __shared__ __align__(16) u16 shH[16 * SH];
  __shared__ float shM[8 * 128];
  const int tid = threadIdx.x, lane = tid & 63, wave = tid >> 6;
  const int g = lane >> 4, q = lane & 15;
  const int r0 = blockIdx.x * 8;

  {
    int row = tid >> 4, c = tid & 15;
    uint4 v = (uint4){0, 0, 0, 0};
    if (tid < 128) v = ((const uint4*)(hv1bf + (size_t)r0 * 128))[tid];
    *(uint4*)(shX + row * SX + c * 8) = v;   // rows 8-15 zero (kept for tail)
  }
  __syncthreads();

  s8v a[4];
#pragma unroll
  for (int t = 0; t < 4; ++t) a[t] = *(const s8v*)(shX + q * SX + t * 32 + g * 8);
#pragma unroll
  for (int cf = 0; cf < 8; ++cf) {
    const int u = wave * 128 + cf * 16 + q;
    const u16* wb = Wint + (size_t)u * 128 + g * 8;
    f4v acc = (f4v){0.f, 0.f, 0.f, 0.f};
#pragma unroll
    for (int t = 0; t < 4; ++t)
      acc = __builtin_amdgcn_mfma_f32_16x16x32_bf16(a[t], *(const s8v*)(wb + t * 32), acc, 0, 0, 0);
    const float bv = binp[u];
#pragma unroll
    for (int r = 0; r < 4; ++r) shH[(g * 4 + r) * SH + u] = f2bf(geluf(acc[r] + bv));
  }
  __syncthreads();

#pragma unroll
  for (int c = 0; c < 2; ++c) {
    const int col = wave * 32 + c * 16 + q;
    const u16* wb = Woutt + (size_t)col * 512 + g * 8;
    s8v Bv[16];
#pragma unroll
    for (int t = 0; t < 16; ++t) Bv[t] = *(const s8v*)(wb + t * 32);
    f4v acc = (f4v){0.f, 0.f, 0.f, 0.f};
#pragma unroll
    for (int t = 0; t < 16; ++t) {
      s8v av = *(const s8v*)(shH + q * SH + t * 32 + g * 8);
      acc = __builtin_amdgcn_mfma_f32_16x16x32_bf16(av, Bv[t], acc, 0, 0, 0);
    }
    const float bv = boutp[col];
#pragma unroll
    for (int r = 0; r < 4; ++r) {
      const int row = g * 4 + r;
      if (row < 8) shM[row * 128 + col] = acc[r] + bv;
    }
  }
  __syncthreads();

#pragma unroll
  for (int i = 0; i < 2; ++i) {
    const int row = wave * 2 + i, gr = r0 + row;
    float x0 = hv1[(size_t)gr * 128 + lane]      + shM[row * 128 + lane];
    float x1 = hv1[(size_t)gr * 128 + 64 + lane] + shM[row * 128 + 64 + lane];
    float s = x0 + x1, ss = x0 * x0 + x1 * x1;
#pragma unroll
    for (int off = 32; off; off >>= 1) { s += __shfl_xor(s, off); ss += __shfl_xor(ss, off); }
    const float mu = s * (1.f / 128.f);
    const float rs = rsqrtf(ss * (1.f / 128.f) - mu * mu + 1e-5f);
    const float mv = mask_V[gr];
    float o0 = mv * (g2[lane]      * (x0 - mu) * rs + be2[lane]);
    float o1 = mv * (g2[lane + 64] * (x1 - mu) * rs + be2[lane + 64]);
    hv2[(size_t)gr * 128 + lane] = o0;
    hv2[(size_t)gr * 128 + 64 + lane] = o1;
    u16 h0 = f2bf(o0), h1 = f2bf(o1);
    shX[row * SX + lane] = h0;          // hv2 bf16 into shX rows 0-7 for the tail
    shX[row * SX + 64 + lane] = h1;
  }
  __syncthreads();

  // tail: T = hv2_rows(16, top 8 valid) @ PRE^T; wave w -> one 128-col region:
  // 0: Qe(W11a), 1: Pe(W11c), 2: QnN(next-layer W1a), 3: PnN(next-layer W1c)
  s8v af[4];
#pragma unroll
  for (int t = 0; t < 4; ++t) af[t] = *(const s8v*)(shX + q * SX + t * 32 + g * 8);
  float* dst = (wave == 0) ? Qe : (wave == 1) ? Pe : (wave == 2) ? QnN : PnN;
  const u16* Wb = PRE + (size_t)(wave * 128) * 128;
#pragma unroll
  for (int cf = 0; cf < 8; ++cf) {
    const int colr = cf * 16 + q;
    const u16* wb = Wb + (size_t)colr * 128 + g * 8;
    f4v acc = (f4v){0.f, 0.f, 0.f, 0.f};
#pragma unroll
    for (int t = 0; t < 4; ++t)
      acc = __builtin_amdgcn_mfma_f32_16x16x32_bf16(af[t], *(const s8v*)(wb + t * 32), acc, 0, 0, 0);
    if (g < 2) {
#pragma unroll
      for (int r = 0; r < 4; ++r)
        dst[(size_t)(r0 + g * 4 + r) * 128 + colr] = acc[r];
    }
  }
}

// ---------------- edge update: init(Q,P-gather) + K=128 MLP + LN3 ----------------
__global__ __launch_bounds__(256, 6) void edge_kernel(
    const float* __restrict__ Qe, const float* __restrict__ Pe,
    const float* __restrict__ hE_src, const int* __restrict__ eidx,
    const u16* __restrict__ W11bT, const u16* __restrict__ W12t, const u16* __restrict__ W13t,
    const float* __restrict__ b11, const float* __restrict__ b12, const float* __restrict__ b13,
    const float* __restrict__ g3, const float* __restrict__ be3,
    float* __restrict__ hE_out) {
  __shared__ __align__(16) u16 buf[2 * 48 * SY];
  __shared__ int sh_idx[48];
  u16* bufA = buf;
  u16* bufB = buf + 48 * SY;

  const int tid = threadIdx.x, lane = tid & 63, wave = tid >> 6;
  const int g = lane >> 4, q = lane & 15;
  const int bid = blockIdx.x, bbase = bid & ~(NN - 1);

  if (tid < 48) sh_idx[tid] = eidx[bid * 48 + tid];
  stage_hE(bufA, hE_src + (size_t)bid * 6144, tid);
  __syncthreads();

  f4v acc[3][2];
  {
    const float* Qr = Qe + (size_t)bid * 128;
#pragma unroll
    for (int c = 0; c < 2; ++c) {
      const int col = wave * 32 + c * 16 + q;
      const float qv = Qr[col];
#pragma unroll
      for (int rt = 0; rt < 3; ++rt)
#pragma unroll
        for (int r = 0; r < 4; ++r) {
          const int row = rt * 16 + g * 4 + r;
          acc[rt][c][r] = qv + Pe[(size_t)(bbase + sh_idx[row]) * 128 + col];
        }
    }
  }
  gemm48k128(bufA, W11bT, wave, lane, acc);
  store_act(acc, bufB, wave, lane, b11);
  __syncthreads();

  zero_acc(acc);
  gemm48k128(bufB, W12t, wave, lane, acc);
  store_act(acc, bufA, wave, lane, b12);
  __syncthreads();

  zero_acc(acc);
  gemm48k128(bufA, W13t, wave, lane, acc);
  __syncthreads();   // all waves done reading bufA; both buffers now dead

  float* shMf = (float*)buf;   // 48*SM*4 = 25344 B <= 26112 B
#pragma unroll
  for (int c = 0; c < 2; ++c) {
    const int col = wave * 32 + c * 16 + q;
    const float bv = b13[col];
#pragma unroll
    for (int rt = 0; rt < 3; ++rt)
#pragma unroll
      for (int r = 0; r < 4; ++r)
        shMf[(rt * 16 + g * 4 + r) * SM + col] = acc[rt][c][r] + bv;
  }
  __syncthreads();

  const float* heb = hE_src + (size_t)bid * 6144;
  float* hob = hE_out + (size_t)bid * 6144;
#pragma unroll 1
  for (int i = 0; i < 12; ++i) {
    const int row = wave * 12 + i;
    float x0 = heb[row * 128 + lane]      + shMf[row * SM + lane];
    float x1 = heb[row * 128 + 64 + lane] + shMf[row * SM + 64 + lane];
    float s = x0 + x1, ss = x0 * x0 + x1 * x1;
#pragma unroll
    for (int off = 32; off; off >>= 1) { s += __shfl_xor(s, off); ss += __shfl_xor(ss, off); }
    const float mu = s * (1.f / 128.f);
    const float rs = rsqrtf(ss * (1.f / 128.f) - mu * mu + 1e-5f);
    hob[row * 128 + lane]      = g3[lane]      * (x0 - mu) * rs + be3[lane];
    hob[row * 128 + 64 + lane] = g3[lane + 64] * (x1 - mu) * rs + be3[lane + 64];
  }
}

extern "C" void kernel_launch(void* const* d_in, const int* in_sizes, int n_in,
                              void* d_out, int out_size, void* d_ws, size_t ws_size,
                              hipStream_t stream) {
  const float* h_V      = (const float*)d_in[0];
  const float* h_E      = (const float*)d_in[1];
  const int*   E_idx    = (const int*)d_in[2];
  const float* mask_V   = (const float*)d_in[3];
  const float* mask_att = (const float*)d_in[4];
  const float* W1   = (const float*)d_in[5];   const float* b1   = (const float*)d_in[6];
  const float* W2   = (const float*)d_in[7];   const float* b2   = (const float*)d_in[8];
  const float* W3   = (const float*)d_in[9];   const float* b3   = (const float*)d_in[10];
  const float* W11  = (const float*)d_in[11];  const float* b11  = (const float*)d_in[12];
  const float* W12  = (const float*)d_in[13];  const float* b12  = (const float*)d_in[14];
  const float* W13  = (const float*)d_in[15];  const float* b13  = (const float*)d_in[16];
  const float* Win  = (const float*)d_in[17];  const float* binp = (const float*)d_in[18];
  const float* Wout = (const float*)d_in[19];  const float* boutp= (const float*)d_in[20];
  const float* g1   = (const float*)d_in[21];  const float* be1  = (const float*)d_in[22];
  const float* g2   = (const float*)d_in[23];  const float* be2  = (const float*)d_in[24];
  const float* g3   = (const float*)d_in[25];  const float* be3  = (const float*)d_in[26];

  float* outV = (float*)d_out;                 // [2,1024,128]
  float* outE = outV + (size_t)BB * NN * HH;   // [2,1024,48,128]

  u16* ws     = (u16*)d_ws;
  u16* W1bT   = ws;                            // 3*128*128
  u16* W11bT  = W1bT  + 3 * 16384;
  u16* W2t    = W11bT + 3 * 16384;
  u16* W3t    = W2t   + 3 * 16384;
  u16* W12t   = W3t   + 3 * 16384;
  u16* W13t   = W12t  + 3 * 16384;
  u16* Wint   = W13t  + 3 * 16384;             // 3*512*128
  u16* Woutt  = Wint  + 3 * 65536;             // 3*128*512
  u16* PREb   = Woutt + 3 * 65536;             // 3*512*128
  u16* hv0bf  = PREb  + 3 * 65536;             // 2048*128
  u16* Pbf    = hv0bf + BB * NN * HH;          // hv1 bf16
  float* Pf   = (float*)(Pbf + BB * NN * HH);  // hv1 f32
  float* Qf   = Pf  + BB * NN * HH;            // hv2 f32
  float* Qn   = Qf  + BB * NN * HH;            // node Q (hv@W1a)
  float* Pn   = Qn  + BB * NN * HH;            // node P (hv@W1c)
  float* Qe   = Pn  + BB * NN * HH;            // edge Q (hv2@W11a)
  float* Pe   = Qe  + BB * NN * HH;            // edge P (hv2@W11c)

  conv_weights<<<512, 256, 0, stream>>>(W1, W2, W3, W11, W12, W13, Win, Wout, h_V,
                                        W1bT, W2t, W3t, W11bT, W12t, W13t, Wint, Woutt,
                                        PREb, hv0bf);

  // layer-0 node P/Q from hv0: PRE_2 slots 2,3 hold W1aT(0), W1cT(0)
  pre_kernel<<<(BB * NN) / 16, 256, 0, stream>>>(
      hv0bf, PREb + 2 * 65536 + 2 * 16384, PREb + 2 * 65536 + 3 * 16384, Qn, Pn);

  for (int l = 0; l < LL; ++l) {
    const float* hv_res  = (l == 0) ? h_V : Qf;
    const float* hE_src  = (l == 0) ? h_E : outE;
    float*       hv2_dst = (l == 2) ? outV : Qf;

    node_msg<<<BB * NN, 256, 0, stream>>>(
        hv_res, Qn, Pn, hE_src, E_idx, mask_att,
        W1bT + l * 16384, W2t + l * 16384, W3t + l * 16384,
        b1 + l * 128, b2 + l * 128, b3 + l * 128,
        g1 + l * 128, be1 + l * 128,
        Pf, Pbf);

    // ffn also computes Qe/Pe (this layer's edge) and Qn/Pn (next layer's node)
    ffn_kernel<<<(BB * NN) / 8, 256, 0, stream>>>(
        Pf, Pbf,
        Wint + l * 65536, binp + l * 512,
        Woutt + l * 65536, boutp + l * 128,
        g2 + l * 128, be2 + l * 128, mask_V,
        PREb + l * 65536,
        hv2_dst, Qe, Pe, Qn, Pn);

    edge_kernel<<<BB * NN, 256, 0, stream>>>(
        Qe, Pe, hE_src, E_idx,
        W11bT + l * 16384, W12t + l * 16384, W13t + l * 16384,
        b11 + l * 128, b12 + l * 128, b13 + l * 128,
        g3 + l * 128, be3 + l * 128,
        outE);
  }
}